// Round 3
// baseline (199.532 us; speedup 1.0000x reference)
//
#include <hip/hip_runtime.h>

#define NUM_CLASSES 19
#define TILES_PER_WAVE 4
#define WAVES_PER_BLOCK 4
// 32768 tiles / (4 tiles/wave * 4 waves/block) = 2048 blocks

// Each 64-lane wave handles 4 whole 32x32 tiles. ALL 16 int4 label loads
// (plus the 4 preds values) are issued up front into registers -> 16+
// outstanding VMEM ops per wave (memory-level parallelism), then masks are
// built and OR-butterflied per tile. One partial per block, no atomics.
__global__ __launch_bounds__(256) void seg_loss_partial(
    const float* __restrict__ preds,
    const int*   __restrict__ targets,
    float*       __restrict__ partial)
{
    const int t    = threadIdx.x;
    const int wave = t >> 6;
    const int lane = t & 63;

    const int tile0 = (blockIdx.x * WAVES_PER_BLOCK + wave) * TILES_PER_WAVE;
    const int row  = lane >> 3;          // base row for j=0 chunk
    const int quad = lane & 7;

    // ---- stage ALL loads first (maximize loads in flight) ----
    int4 v[TILES_PER_WAVE][4];
    #pragma unroll
    for (int i = 0; i < TILES_PER_WAVE; ++i) {
        const int n  = tile0 + i;        // tile = b*1024 + by*32 + bx
        const int* base = targets + ((long long)(n >> 10) << 20)
                                  + (long long)(((n >> 5) & 31) << 5) * 1024
                                  + ((n & 31) << 5);
        #pragma unroll
        for (int j = 0; j < 4; ++j) {
            // int4 index j*64+lane -> row (idx>>3), quad (idx&7)
            v[i][j] = *(const int4*)(base + (j * 8 + row) * 1024 + quad * 4);
        }
    }

    const int cl = (lane < NUM_CLASSES) ? lane : 0;   // clamp to stay in-bounds
    float x[TILES_PER_WAVE];
    #pragma unroll
    for (int i = 0; i < TILES_PER_WAVE; ++i)
        x[i] = preds[(tile0 + i) * NUM_CLASSES + cl];

    // ---- process ----
    float loss = 0.0f;
    #pragma unroll
    for (int i = 0; i < TILES_PER_WAVE; ++i) {
        unsigned mask = 0u;
        #pragma unroll
        for (int j = 0; j < 4; ++j) {
            mask |= (1u << v[i][j].x) | (1u << v[i][j].y)
                  | (1u << v[i][j].z) | (1u << v[i][j].w);
        }
        mask |= __shfl_xor(mask, 1);
        mask |= __shfl_xor(mask, 2);
        mask |= __shfl_xor(mask, 4);
        mask |= __shfl_xor(mask, 8);
        mask |= __shfl_xor(mask, 16);
        mask |= __shfl_xor(mask, 32);

        if (lane < NUM_CLASSES) {
            const float xi = x[i];
            const float tv = ((mask >> lane) & 1u) ? 1.0f : 0.0f;
            // stable BCE term: softplus(x) - t*x
            const float sp = fmaxf(xi, 0.0f) + log1pf(__expf(-fabsf(xi)));
            loss += sp - tv * xi;
        }
    }

    // wave-level sum
    loss += __shfl_xor(loss, 1);
    loss += __shfl_xor(loss, 2);
    loss += __shfl_xor(loss, 4);
    loss += __shfl_xor(loss, 8);
    loss += __shfl_xor(loss, 16);
    loss += __shfl_xor(loss, 32);

    __shared__ float wsum[WAVES_PER_BLOCK];
    if (lane == 0) wsum[wave] = loss;
    __syncthreads();
    if (t == 0)
        partial[blockIdx.x] = wsum[0] + wsum[1] + wsum[2] + wsum[3];
}

__global__ __launch_bounds__(256) void seg_loss_reduce(
    const float* __restrict__ partial,
    float*       __restrict__ out,
    float inv_total, int n)
{
    float s = 0.0f;
    for (int i = threadIdx.x; i < n; i += 256) s += partial[i];

    s += __shfl_xor(s, 1);
    s += __shfl_xor(s, 2);
    s += __shfl_xor(s, 4);
    s += __shfl_xor(s, 8);
    s += __shfl_xor(s, 16);
    s += __shfl_xor(s, 32);

    __shared__ float wsum[4];
    const int wave = threadIdx.x >> 6;
    const int lane = threadIdx.x & 63;
    if (lane == 0) wsum[wave] = s;
    __syncthreads();
    if (threadIdx.x == 0)
        out[0] = (wsum[0] + wsum[1] + wsum[2] + wsum[3]) * inv_total;
}

extern "C" void kernel_launch(void* const* d_in, const int* in_sizes, int n_in,
                              void* d_out, int out_size, void* d_ws, size_t ws_size,
                              hipStream_t stream) {
    const float* preds   = (const float*)d_in[0];
    const int*   targets = (const int*)d_in[1];
    float*       out     = (float*)d_out;
    float*       partial = (float*)d_ws;

    const int n_tiles  = in_sizes[0] / NUM_CLASSES;                    // 32768
    const int n_blocks = n_tiles / (TILES_PER_WAVE * WAVES_PER_BLOCK); // 2048
    const float inv_total = 1.0f / (float)(n_tiles * NUM_CLASSES);

    seg_loss_partial<<<n_blocks, 256, 0, stream>>>(preds, targets, partial);
    seg_loss_reduce<<<1, 256, 0, stream>>>(partial, out, inv_total, n_blocks);
}

// Round 4
// 198.543 us; speedup vs baseline: 1.0050x; 1.0050x over previous
//
#include <hip/hip_runtime.h>

#define NUM_CLASSES 19
// 1 tile per wave, 4 waves per block -> 32768/4 = 8192 blocks.
// Minimal VGPR (4 int4 in flight + 1 pred), max occupancy, short waves.

__global__ __launch_bounds__(256) void seg_loss_partial(
    const float* __restrict__ preds,
    const int*   __restrict__ targets,
    float*       __restrict__ partial)
{
    const int t    = threadIdx.x;
    const int wave = t >> 6;
    const int lane = t & 63;

    const int n  = blockIdx.x * 4 + wave;        // tile id 0..32767
    const int b  = n >> 10;
    const int by = (n >> 5) & 31;
    const int bx = n & 31;
    // element offsets fit in 32-bit (max 32M) -> cheap addressing
    const int* base = targets + (b << 20) + ((by << 5) << 10) + (bx << 5);

    const int row  = lane >> 3;                  // 0..7
    const int quad = lane & 7;                   // 0..7

    // 4 independent int4 loads (tile rows row, row+8, row+16, row+24)
    const int4 v0 = *(const int4*)(base + ( 0 + row) * 1024 + quad * 4);
    const int4 v1 = *(const int4*)(base + ( 8 + row) * 1024 + quad * 4);
    const int4 v2 = *(const int4*)(base + (16 + row) * 1024 + quad * 4);
    const int4 v3 = *(const int4*)(base + (24 + row) * 1024 + quad * 4);
    const float x = preds[n * NUM_CLASSES + (lane < NUM_CLASSES ? lane : 0)];

    unsigned mask = (1u << v0.x) | (1u << v0.y) | (1u << v0.z) | (1u << v0.w)
                  | (1u << v1.x) | (1u << v1.y) | (1u << v1.z) | (1u << v1.w)
                  | (1u << v2.x) | (1u << v2.y) | (1u << v2.z) | (1u << v2.w)
                  | (1u << v3.x) | (1u << v3.y) | (1u << v3.z) | (1u << v3.w);

    mask |= __shfl_xor(mask, 1);
    mask |= __shfl_xor(mask, 2);
    mask |= __shfl_xor(mask, 4);
    mask |= __shfl_xor(mask, 8);
    mask |= __shfl_xor(mask, 16);
    mask |= __shfl_xor(mask, 32);

    float loss = 0.0f;
    if (lane < NUM_CLASSES) {
        const float tv = ((mask >> lane) & 1u) ? 1.0f : 0.0f;
        // stable BCE term: softplus(x) - t*x
        const float sp = fmaxf(x, 0.0f) + log1pf(__expf(-fabsf(x)));
        loss = sp - tv * x;
    }

    loss += __shfl_xor(loss, 1);
    loss += __shfl_xor(loss, 2);
    loss += __shfl_xor(loss, 4);
    loss += __shfl_xor(loss, 8);
    loss += __shfl_xor(loss, 16);
    loss += __shfl_xor(loss, 32);

    __shared__ float wsum[4];
    if (lane == 0) wsum[wave] = loss;
    __syncthreads();
    if (t == 0)
        partial[blockIdx.x] = wsum[0] + wsum[1] + wsum[2] + wsum[3];
}

__global__ __launch_bounds__(256) void seg_loss_reduce(
    const float* __restrict__ partial,
    float*       __restrict__ out,
    float inv_total, int n)
{
    float s = 0.0f;
    for (int i = threadIdx.x; i < n; i += 256) s += partial[i];

    s += __shfl_xor(s, 1);
    s += __shfl_xor(s, 2);
    s += __shfl_xor(s, 4);
    s += __shfl_xor(s, 8);
    s += __shfl_xor(s, 16);
    s += __shfl_xor(s, 32);

    __shared__ float wsum[4];
    const int wave = threadIdx.x >> 6;
    const int lane = threadIdx.x & 63;
    if (lane == 0) wsum[wave] = s;
    __syncthreads();
    if (threadIdx.x == 0)
        out[0] = (wsum[0] + wsum[1] + wsum[2] + wsum[3]) * inv_total;
}

extern "C" void kernel_launch(void* const* d_in, const int* in_sizes, int n_in,
                              void* d_out, int out_size, void* d_ws, size_t ws_size,
                              hipStream_t stream) {
    const float* preds   = (const float*)d_in[0];
    const int*   targets = (const int*)d_in[1];
    float*       out     = (float*)d_out;
    float*       partial = (float*)d_ws;

    const int n_tiles  = in_sizes[0] / NUM_CLASSES;   // 32768
    const int n_blocks = n_tiles / 4;                 // 8192
    const float inv_total = 1.0f / (float)(n_tiles * NUM_CLASSES);

    seg_loss_partial<<<n_blocks, 256, 0, stream>>>(preds, targets, partial);
    seg_loss_reduce<<<1, 256, 0, stream>>>(partial, out, inv_total, n_blocks);
}

// Round 5
// 197.675 us; speedup vs baseline: 1.0094x; 1.0044x over previous
//
#include <hip/hip_runtime.h>

#define NUM_CLASSES 19

// One block per 32-row x 1024-col slab of targets (= one row of 32 tiles,
// 128 KB CONTIGUOUS). Per iteration the block int4-loads one full 4 KB image
// row; over 32 iterations it streams its slab linearly (fill-like HBM
// pattern, no 4 KB-strided bursts). Thread t always covers columns
// [t*4 .. t*4+3] -> its tile (t>>3) is FIXED: accumulate a private presence
// mask, fold 8 threads/tile with 3 shuffle-ORs, stage 32 tile masks in LDS,
// then 32x19 BCE terms + block reduction -> one partial per block.
__global__ __launch_bounds__(256) void seg_loss_partial(
    const float* __restrict__ preds,
    const int*   __restrict__ targets,
    float*       __restrict__ partial)
{
    const int tid = threadIdx.x;
    // blockIdx.x = b*32 + s : batch b, slab (tile-row) s
    // slab base element = b*1024*1024 + s*32*1024 = blockIdx.x * 32768
    const int* base = targets + (blockIdx.x << 15);

    unsigned mask = 0u;
    #pragma unroll 4
    for (int r = 0; r < 32; ++r) {
        const int4 v = *(const int4*)(base + (r << 10) + (tid << 2));
        mask |= (1u << v.x) | (1u << v.y) | (1u << v.z) | (1u << v.w);
    }

    // fold the 8 consecutive threads sharing a tile (groups of 8 sit inside
    // one 64-lane wave)
    mask |= __shfl_xor(mask, 1);
    mask |= __shfl_xor(mask, 2);
    mask |= __shfl_xor(mask, 4);

    __shared__ unsigned tile_mask[32];
    if ((tid & 7) == 0) tile_mask[tid >> 3] = mask;
    __syncthreads();

    // BCE terms: tile = tid>>3 (32 tiles x 8 threads), classes c, c+8, c+16
    const int tile = tid >> 3;
    const int n    = (blockIdx.x << 5) + tile;      // global tile id
    const unsigned m = tile_mask[tile];
    float loss = 0.0f;
    #pragma unroll
    for (int j = 0; j < 3; ++j) {
        const int c = (tid & 7) + (j << 3);
        if (c < NUM_CLASSES) {
            const float x  = preds[n * NUM_CLASSES + c];
            const float tv = ((m >> c) & 1u) ? 1.0f : 0.0f;
            // stable BCE term: softplus(x) - t*x
            const float sp = fmaxf(x, 0.0f) + log1pf(__expf(-fabsf(x)));
            loss += sp - tv * x;
        }
    }

    // block reduction
    loss += __shfl_xor(loss, 1);
    loss += __shfl_xor(loss, 2);
    loss += __shfl_xor(loss, 4);
    loss += __shfl_xor(loss, 8);
    loss += __shfl_xor(loss, 16);
    loss += __shfl_xor(loss, 32);

    __shared__ float wsum[4];
    if ((tid & 63) == 0) wsum[tid >> 6] = loss;
    __syncthreads();
    if (tid == 0)
        partial[blockIdx.x] = wsum[0] + wsum[1] + wsum[2] + wsum[3];
}

__global__ __launch_bounds__(256) void seg_loss_reduce(
    const float* __restrict__ partial,
    float*       __restrict__ out,
    float inv_total, int nblocks)
{
    float s = 0.0f;
    for (int i = threadIdx.x; i < nblocks; i += 256) s += partial[i];

    s += __shfl_xor(s, 1);
    s += __shfl_xor(s, 2);
    s += __shfl_xor(s, 4);
    s += __shfl_xor(s, 8);
    s += __shfl_xor(s, 16);
    s += __shfl_xor(s, 32);

    __shared__ float wsum[4];
    const int wave = threadIdx.x >> 6;
    const int lane = threadIdx.x & 63;
    if (lane == 0) wsum[wave] = s;
    __syncthreads();
    if (threadIdx.x == 0)
        out[0] = (wsum[0] + wsum[1] + wsum[2] + wsum[3]) * inv_total;
}

extern "C" void kernel_launch(void* const* d_in, const int* in_sizes, int n_in,
                              void* d_out, int out_size, void* d_ws, size_t ws_size,
                              hipStream_t stream) {
    const float* preds   = (const float*)d_in[0];
    const int*   targets = (const int*)d_in[1];
    float*       out     = (float*)d_out;
    float*       partial = (float*)d_ws;

    const int n_tiles  = in_sizes[0] / NUM_CLASSES;   // 32768
    const int n_blocks = n_tiles / 32;                // 1024 slabs
    const float inv_total = 1.0f / (float)(n_tiles * NUM_CLASSES);

    seg_loss_partial<<<n_blocks, 256, 0, stream>>>(preds, targets, partial);
    seg_loss_reduce<<<1, 256, 0, stream>>>(partial, out, inv_total, n_blocks);
}